// Round 13
// baseline (169.042 us; speedup 1.0000x reference)
//
#include <hip/hip_runtime.h>
#include <hip/hip_bf16.h>
#include <math.h>

#define VOCAB 100000
#define TOPK  20
#define EMB   300
#define NTOK  (64*256)
#define NVT   1563          // ceil(VOCAB/64) v-tiles
#define NESL  5             // e-slices of 64 cols

typedef __attribute__((ext_vector_type(8))) short short8;   // 8 bf16 = 4 VGPR
typedef __attribute__((ext_vector_type(4))) float f32x4;

static __device__ inline short f2bf(float f) {
    __hip_bfloat16 h = __float2bfloat16(f);
    short s; __builtin_memcpy(&s, &h, 2);
    return s;
}

// ---------------------------------------------------------------------------
// prep: aT[e][d] = bf16(a[d][e]), zero-padded to 320x320.
// ---------------------------------------------------------------------------
__global__ void prep_kernel(const float* __restrict__ A, short* __restrict__ aT)
{
    const int e = blockIdx.x;                 // 0..319
    for (int d = threadIdx.x; d < 320; d += 256) {
        float f = (e < EMB && d < EMB) ? A[(size_t)d * EMB + e] : 0.f;
        aT[e * 320 + d] = f2bf(f);
    }
}

// ---------------------------------------------------------------------------
// score: s[v] = sum_e tanh( emb[v,:] . a[:,e] ) * b[e]  via bf16 MFMA.
// r12 lesson: all LDS-B designs sit at ~0.7 ds_read/MFMA and are LDS-pipe
// bound (~77us regardless of occupancy). Fix: B-FRAGMENTS IN REGISTERS,
// sized INSIDE the hard 128-VGPR cap (r8's 200-reg version spilled):
// wave = 32 rows x 32 cols x K-half -> bAll[2][5] = 40 VGPR only.
// Block = 64 rows x 64 e-cols, 8 waves = 2mg x 2ng x 2kh. Per k-step:
// 2 A-reads + 4 MFMA (no B reads). LDS = A-tile 40KB + Sred = 41KB ->
// 3 blocks/CU, 6 waves/SIMD; staging is direct global->cvt->LDS (latency
// hidden by co-resident blocks). kh-exchange (16KB) overlays the dead
// A-region after the k-loop's barrier.
// e-dim: 5 slices of 64 cols; bid mapping XCD-groups the 5 esl-siblings of
// a v-tile (r11: FETCH stayed ~1x emb -> L3 absorbs the 5x re-read).
// Output: 5 partial planes Sp[esl][v]; sum_kernel collapses to one plane.
// ---------------------------------------------------------------------------
__global__ __launch_bounds__(512) void score_kernel(
    const float* __restrict__ emb, const short* __restrict__ aT,
    const float* __restrict__ B, float* __restrict__ Sp)
{
    __shared__ short8 EsS[64 * 40];      // 40960 B : A tile (Scr overlays)
    __shared__ float  Sred[128];         // 512 B

    const int bid = blockIdx.x;
    const int low = bid % 40;
    const int esl = low >> 3;                    // 0..4
    const int vt  = (bid / 40) * 8 + (low & 7);  // XCD-grouped v-tile
    if (vt >= NVT) return;
    const int v0 = vt * 64;

    const int t   = threadIdx.x;
    const int lid = t & 63;
    const int w   = t >> 6;        // 0..7
    const int kh  = w >> 2;        // k-half 0..1
    const int mg  = (w >> 1) & 1;  // m-pair (rows mg*32..mg*32+31)
    const int ng  = w & 1;         // n-pair (cols ng*32..ng*32+31)
    const int lm  = lid & 15;
    const int lk  = lid >> 4;
    const int xm  = lm & 7;        // row%8 == lm%8 (offsets are mult of 16)
    const int cell = mg * 2 + ng;  // 0..3

    // ---- B-fragments -> registers (10 x b128 from L2-resident aT)
    const short8* aT8 = (const short8*)aT;
    short8 ball[2][5];
    float  bcol[2];
#pragma unroll
    for (int n = 0; n < 2; ++n) {
        const int e = esl * 64 + ng * 32 + n * 16 + lm;   // global e-col
#pragma unroll
        for (int ks = 0; ks < 5; ++ks)
            ball[n][ks] = aT8[e * 40 + kh * 20 + ks * 4 + lk];
        bcol[n] = (e < EMB) ? B[e] : 0.f;
    }

    // ---- stage A tile: 64 rows x 40 chunks, direct global->cvt->LDS,
    //      XOR-swizzled (chunk ^ row&7); rows beyond VOCAB -> zeros.
    {
        const float4* esrc = (const float4*)(emb + (size_t)v0 * EMB);
#pragma unroll
        for (int j = 0; j < 5; ++j) {
            const int i = t + j * 512;           // chunk index: 64*37 = 2368
            if (i < 2368) {
                const int row = i / 37, c = i - row * 37;
                float4 f0 = make_float4(0.f, 0.f, 0.f, 0.f);
                float4 f1 = make_float4(0.f, 0.f, 0.f, 0.f);
                if (v0 + row < VOCAB) {
                    f0 = esrc[row * 75 + c * 2];
                    f1 = esrc[row * 75 + c * 2 + 1];
                }
                short8 val;
                val[0] = f2bf(f0.x); val[1] = f2bf(f0.y);
                val[2] = f2bf(f0.z); val[3] = f2bf(f0.w);
                val[4] = f2bf(f1.x); val[5] = f2bf(f1.y);
                val[6] = f2bf(f1.z); val[7] = f2bf(f1.w);
                EsS[row * 40 + (c ^ (row & 7))] = val;
            }
        }
        if (t < 64) {    // chunk 37: floats 296..299 + 4 zero-pad
            float4 f = make_float4(0.f, 0.f, 0.f, 0.f);
            if (v0 + t < VOCAB) f = esrc[t * 75 + 74];
            short8 v37 = (short8){0, 0, 0, 0, 0, 0, 0, 0};
            v37[0] = f2bf(f.x); v37[1] = f2bf(f.y);
            v37[2] = f2bf(f.z); v37[3] = f2bf(f.w);
            EsS[t * 40 + (37 ^ (t & 7))] = v37;
        }
        if (t < 128) {   // chunks 38,39: pure zero pad
            const int row = t >> 1, q = 38 + (t & 1);
            EsS[row * 40 + (q ^ (row & 7))] = (short8){0, 0, 0, 0, 0, 0, 0, 0};
        }
    }
    __syncthreads();                             // B1: A tile ready

    // ---- k-loop: 5 steps; 2 A ds_reads + 4 MFMA per step (B in regs)
    f32x4 acc[2][2];
#pragma unroll
    for (int mt = 0; mt < 2; ++mt)
#pragma unroll
        for (int n = 0; n < 2; ++n)
            acc[mt][n] = (f32x4){0.f, 0.f, 0.f, 0.f};

    const int rb0 = (mg * 32 + lm) * 40;
    const int rb1 = (mg * 32 + 16 + lm) * 40;
#pragma unroll
    for (int ks = 0; ks < 5; ++ks) {
        const int kx = (kh * 20 + ks * 4 + lk) ^ xm;
        short8 af0 = EsS[rb0 + kx];
        short8 af1 = EsS[rb1 + kx];
        acc[0][0] = __builtin_amdgcn_mfma_f32_16x16x32_bf16(af0, ball[0][ks], acc[0][0], 0, 0, 0);
        acc[0][1] = __builtin_amdgcn_mfma_f32_16x16x32_bf16(af0, ball[1][ks], acc[0][1], 0, 0, 0);
        acc[1][0] = __builtin_amdgcn_mfma_f32_16x16x32_bf16(af1, ball[0][ks], acc[1][0], 0, 0, 0);
        acc[1][1] = __builtin_amdgcn_mfma_f32_16x16x32_bf16(af1, ball[1][ks], acc[1][1], 0, 0, 0);
    }
    __syncthreads();                             // B2: EsS reads done

    // ---- kh-exchange (pre-tanh) via 16 KB scratch overlaying EsS
    float4* Scr4 = (float4*)EsS;                 // [4 cell][64 lane][4 mtn]
    if (kh == 1) {
#pragma unroll
        for (int mt = 0; mt < 2; ++mt)
#pragma unroll
            for (int n = 0; n < 2; ++n)
                Scr4[(cell * 64 + lid) * 4 + mt * 2 + n] = *(float4*)&acc[mt][n];
    }
    __syncthreads();                             // B3: partials shipped

    if (kh == 0) {
        float part[2][4];
#pragma unroll
        for (int mt = 0; mt < 2; ++mt) {
            float4 o0 = Scr4[(cell * 64 + lid) * 4 + mt * 2 + 0];
            float4 o1 = Scr4[(cell * 64 + lid) * 4 + mt * 2 + 1];
#pragma unroll
            for (int i = 0; i < 4; ++i) {
                float x0 = acc[mt][0][i] + (&o0.x)[i];
                float x1 = acc[mt][1][i] + (&o1.x)[i];
                float c0 = fminf(fmaxf(x0, -15.f), 15.f);
                float c1 = fminf(fmaxf(x1, -15.f), 15.f);
                float e0 = __expf(2.f * c0);
                float e1 = __expf(2.f * c1);
                part[mt][i] = __fdividef(e0 - 1.f, e0 + 1.f) * bcol[0]
                            + __fdividef(e1 - 1.f, e1 + 1.f) * bcol[1];
            }
        }
#pragma unroll
        for (int m = 1; m <= 8; m <<= 1)
#pragma unroll
            for (int mt = 0; mt < 2; ++mt)
#pragma unroll
                for (int i = 0; i < 4; ++i)
                    part[mt][i] += __shfl_xor(part[mt][i], m);
        if (lm == 0) {
#pragma unroll
            for (int mt = 0; mt < 2; ++mt)
#pragma unroll
                for (int i = 0; i < 4; ++i)
                    Sred[ng * 64 + mg * 32 + mt * 16 + lk * 4 + i] = part[mt][i];
        }
    }
    __syncthreads();                             // B4: Sred ready

    if (t < 64) {
        const int v = v0 + t;
        if (v < VOCAB) Sp[(size_t)esl * VOCAB + v] = Sred[t] + Sred[64 + t];
    }
}

// ---------------------------------------------------------------------------
// sum: collapse 5 partial planes into one (coalesced, ~2.4 MB traffic).
// ---------------------------------------------------------------------------
__global__ __launch_bounds__(256) void sum_kernel(
    const float* __restrict__ Sp, float* __restrict__ Ss)
{
    const int v = blockIdx.x * 256 + threadIdx.x;
    if (v < VOCAB)
        Ss[v] = Sp[v] + Sp[VOCAB + v] + Sp[2 * VOCAB + v]
              + Sp[3 * VOCAB + v] + Sp[4 * VOCAB + v];
}

// ---------------------------------------------------------------------------
// attend: per token gather 20 neighbor scores (single plane), softmax,
// weighted emb sum. One wave per token.
// ---------------------------------------------------------------------------
__global__ __launch_bounds__(256) void attend_kernel(
    const int* __restrict__ text, const int* __restrict__ neighbors,
    const float* __restrict__ emb, const float* __restrict__ S,
    float* __restrict__ out)
{
    const int lane = threadIdx.x & 63;
    const int wv   = threadIdx.x >> 6;
    const int tok  = blockIdx.x * 4 + wv;

    const int tid = text[tok];

    int   nbk = 0;
    float sc  = -1e30f;
    if (lane < TOPK) {
        nbk = neighbors[tid * TOPK + lane];
        sc  = S[nbk];
    }

    float mx = sc;
#pragma unroll
    for (int m = 16; m >= 1; m >>= 1)
        mx = fmaxf(mx, __shfl_xor(mx, m));

    float ex = (lane < TOPK) ? expf(sc - mx) : 0.f;
    float sum = ex;
#pragma unroll
    for (int m = 16; m >= 1; m >>= 1)
        sum += __shfl_xor(sum, m);
    float att = ex / sum;

    float acc0 = 0.f, acc1 = 0.f, acc2 = 0.f, acc3 = 0.f, acc4 = 0.f;
    const bool has5 = (lane < EMB - 256);
#pragma unroll 4
    for (int k = 0; k < TOPK; ++k) {
        const float wgt = __shfl(att, k);
        const int   id  = __shfl(nbk, k);
        const float* row = emb + (size_t)id * EMB;
        acc0 = fmaf(wgt, row[lane      ], acc0);
        acc1 = fmaf(wgt, row[lane +  64], acc1);
        acc2 = fmaf(wgt, row[lane + 128], acc2);
        acc3 = fmaf(wgt, row[lane + 192], acc3);
        if (has5) acc4 = fmaf(wgt, row[lane + 256], acc4);
    }

    float* orow = out + (size_t)tok * EMB;
    orow[lane      ] = acc0;
    orow[lane +  64] = acc1;
    orow[lane + 128] = acc2;
    orow[lane + 192] = acc3;
    if (has5) orow[lane + 256] = acc4;
}

extern "C" void kernel_launch(void* const* d_in, const int* in_sizes, int n_in,
                              void* d_out, int out_size, void* d_ws, size_t ws_size,
                              hipStream_t stream) {
    const int*   text      = (const int*)d_in[0];
    const int*   neighbors = (const int*)d_in[1];
    const float* emb       = (const float*)d_in[2];
    const float* A         = (const float*)d_in[3];
    const float* B         = (const float*)d_in[4];
    float*       out       = (float*)d_out;

    char* ws = (char*)d_ws;
    float* Sp = (float*)ws;                 // 5 x 400,000 B partial planes
    float* Ss = (float*)(ws + 2000000);     // 400,000 B summed plane
    short* aT = (short*)(ws + 2400000);     // 204,800 B (16B-aligned)

    prep_kernel<<<320, 256, 0, stream>>>(A, aT);
    score_kernel<<<40 * ((NVT + 7) / 8), 512, 0, stream>>>(emb, aT, B, Sp);
    sum_kernel<<<(VOCAB + 255) / 256, 256, 0, stream>>>(Sp, Ss);
    attend_kernel<<<NTOK / 4, 256, 0, stream>>>(text, neighbors, emb, Ss, out);
}

// Round 14
// 150.585 us; speedup vs baseline: 1.1226x; 1.1226x over previous
//
#include <hip/hip_runtime.h>
#include <hip/hip_bf16.h>
#include <math.h>

#define VOCAB 100000
#define TOPK  20
#define EMB   300
#define NTOK  (64*256)
#define NVT   1563          // ceil(VOCAB/64) v-tiles
#define NVGS  102           // v-groups per e-slice (5*102 = 510 blocks <= 512)

typedef __attribute__((ext_vector_type(8))) short short8;   // 8 bf16 = 4 VGPR
typedef __attribute__((ext_vector_type(4))) float f32x4;

static __device__ inline short f2bf(float f) {
    __hip_bfloat16 h = __float2bfloat16(f);
    short s; __builtin_memcpy(&s, &h, 2);
    return s;
}

// ---------------------------------------------------------------------------
// prep: aT[e][d] = bf16(a[d][e]), zero-padded to 320x320.
// ---------------------------------------------------------------------------
__global__ void prep_kernel(const float* __restrict__ A, short* __restrict__ aT)
{
    const int e = blockIdx.x;                 // 0..319
    for (int d = threadIdx.x; d < 320; d += 256) {
        float f = (e < EMB && d < EMB) ? A[(size_t)d * EMB + e] : 0.f;
        aT[e * 320 + d] = f2bf(f);
    }
}

// ---------------------------------------------------------------------------
// score: s[v] = sum_e tanh( emb[v,:] . a[:,e] ) * b[e]  via bf16 MFMA.
// r13 lesson: non-persistent blocks let LLVM sink the B-fragment loads into
// the k-loop (VGPR=40 proved ball never stayed resident) -> per-MFMA L2
// latency. Fix: PERSISTENT blocks -- ball[2][5] (40 VGPR) loaded once,
// consumed ~15 tiles; sinking would 15x the loads, so the compiler keeps it
// (asm memory-fence as insurance). Peak regs ~100 < the hard 128 cap.
// Block = (esl of 64 e-cols, vg), walks tiles vt = vg + tt*NVGS.
// 8 waves = 2mg x 2ng x 2kh; wave = 32 rows x 32 cols x K-half(160).
// Per k-step: 2 A ds_reads + 4 MFMA, B from regs.
// LDS: EsS 40KB + Scr 16KB (separate; 16B lane stride = 4-way, ~free) +
// Sred = 57.9 KB -> 2 blocks/CU; 3 barriers/tile, staging overlapped into
// the B2->B3 window. Output: 5 partial planes; sum_kernel collapses.
// ---------------------------------------------------------------------------
__global__ __launch_bounds__(512) void score_kernel(
    const float* __restrict__ emb, const short* __restrict__ aT,
    const float* __restrict__ B, float* __restrict__ Sp)
{
    __shared__ short8 EsS[64 * 40];      // 40960 B : A tile (swizzled)
    __shared__ float4 Scr[16 * 64];      // 16384 B : kh-exchange scratch
    __shared__ float  Sred[128];         // 512 B

    const int bid = blockIdx.x;
    const int esl = bid / NVGS;          // 0..4
    const int vg  = bid % NVGS;          // 0..101

    const int t   = threadIdx.x;
    const int lid = t & 63;
    const int w   = t >> 6;        // 0..7
    const int kh  = w >> 2;        // k-half 0..1
    const int mg  = (w >> 1) & 1;  // m-pair (rows mg*32..mg*32+31)
    const int ng  = w & 1;         // n-pair (cols ng*32..ng*32+31)
    const int lm  = lid & 15;
    const int lk  = lid >> 4;
    const int xm  = lm & 7;        // row%8 == lm%8 (offsets mult of 16)
    const int cell = mg * 2 + ng;  // 0..3

    // ---- B-fragments -> registers ONCE (10 b128 from L2; reused ~15 tiles)
    const short8* aT8 = (const short8*)aT;
    short8 ball[2][5];
    float  bcol[2];
#pragma unroll
    for (int n = 0; n < 2; ++n) {
        const int e = esl * 64 + ng * 32 + n * 16 + lm;
#pragma unroll
        for (int ks = 0; ks < 5; ++ks)
            ball[n][ks] = aT8[e * 40 + kh * 20 + ks * 4 + lk];
        bcol[n] = (e < EMB) ? B[e] : 0.f;
    }
    asm volatile("" ::: "memory");   // pin ball/bcol in regs (no re-load)

    const int rb0 = (mg * 32 + lm) * 40;
    const int rb1 = (mg * 32 + 16 + lm) * 40;

    // zero-pad chunks 38,39 once (never overwritten by STAGE)
    if (t < 128) {
        const int row = t >> 1, q = 38 + (t & 1);
        EsS[row * 40 + (q ^ (row & 7))] = (short8){0, 0, 0, 0, 0, 0, 0, 0};
    }

#define STAGE(V0) do {                                                        \
    const float4* esrc = (const float4*)(emb + (size_t)(V0) * EMB);           \
    _Pragma("unroll")                                                         \
    for (int j = 0; j < 5; ++j) {                                             \
        const int i = t + j * 512;                                            \
        if (i < 2368) {                                                       \
            const int row = i / 37, c = i - row * 37;                         \
            float4 f0 = make_float4(0.f, 0.f, 0.f, 0.f);                      \
            float4 f1 = make_float4(0.f, 0.f, 0.f, 0.f);                      \
            if ((V0) + row < VOCAB) {                                         \
                f0 = esrc[row * 75 + c * 2];                                  \
                f1 = esrc[row * 75 + c * 2 + 1];                              \
            }                                                                 \
            short8 val;                                                       \
            val[0] = f2bf(f0.x); val[1] = f2bf(f0.y);                         \
            val[2] = f2bf(f0.z); val[3] = f2bf(f0.w);                         \
            val[4] = f2bf(f1.x); val[5] = f2bf(f1.y);                         \
            val[6] = f2bf(f1.z); val[7] = f2bf(f1.w);                         \
            EsS[row * 40 + (c ^ (row & 7))] = val;                            \
        }                                                                     \
    }                                                                         \
    if (t < 64) {   /* chunk 37: floats 296..299 + zero pad */                \
        float4 f = make_float4(0.f, 0.f, 0.f, 0.f);                           \
        if ((V0) + t < VOCAB) f = esrc[t * 75 + 74];                          \
        short8 v37 = (short8){0, 0, 0, 0, 0, 0, 0, 0};                        \
        v37[0] = f2bf(f.x); v37[1] = f2bf(f.y);                               \
        v37[2] = f2bf(f.z); v37[3] = f2bf(f.w);                               \
        EsS[t * 40 + (37 ^ (t & 7))] = v37;                                   \
    }                                                                         \
} while (0)

    const int ntiles = (NVT - vg + NVGS - 1) / NVGS;   // 15 or 16

    STAGE(vg * 64);                  // tile 0
    __syncthreads();                 // B1 (once)

    for (int tt = 0; tt < ntiles; ++tt) {
        const int v0 = (vg + tt * NVGS) * 64;

        // ---- k-loop: 5 steps; 2 A ds_reads + 4 MFMA per step (B in regs)
        f32x4 acc[2][2];
#pragma unroll
        for (int mt = 0; mt < 2; ++mt)
#pragma unroll
            for (int n = 0; n < 2; ++n)
                acc[mt][n] = (f32x4){0.f, 0.f, 0.f, 0.f};
#pragma unroll
        for (int ks = 0; ks < 5; ++ks) {
            const int kx = (kh * 20 + ks * 4 + lk) ^ xm;
            short8 af0 = EsS[rb0 + kx];
            short8 af1 = EsS[rb1 + kx];
            acc[0][0] = __builtin_amdgcn_mfma_f32_16x16x32_bf16(af0, ball[0][ks], acc[0][0], 0, 0, 0);
            acc[0][1] = __builtin_amdgcn_mfma_f32_16x16x32_bf16(af0, ball[1][ks], acc[0][1], 0, 0, 0);
            acc[1][0] = __builtin_amdgcn_mfma_f32_16x16x32_bf16(af1, ball[0][ks], acc[1][0], 0, 0, 0);
            acc[1][1] = __builtin_amdgcn_mfma_f32_16x16x32_bf16(af1, ball[1][ks], acc[1][1], 0, 0, 0);
        }
        __syncthreads();                             // B2: EsS reads done

        // ---- kh=1 ships partials; ALL threads stage next tile (overlap)
        if (kh == 1) {
#pragma unroll
            for (int mt = 0; mt < 2; ++mt)
#pragma unroll
                for (int n = 0; n < 2; ++n)
                    Scr[((mt * 2 + n) * 4 + cell) * 64 + lid] = *(float4*)&acc[mt][n];
        }
        if (tt + 1 < ntiles) STAGE((vg + (tt + 1) * NVGS) * 64);
        __syncthreads();                             // B3: Scr + staging done

        // ---- epilogue (kh=0): combine, tanh, dot b, shfl-reduce
        if (kh == 0) {
            float part[2][4];
#pragma unroll
            for (int mt = 0; mt < 2; ++mt) {
                float4 o0 = Scr[((mt * 2 + 0) * 4 + cell) * 64 + lid];
                float4 o1 = Scr[((mt * 2 + 1) * 4 + cell) * 64 + lid];
#pragma unroll
                for (int i = 0; i < 4; ++i) {
                    float x0 = acc[mt][0][i] + (&o0.x)[i];
                    float x1 = acc[mt][1][i] + (&o1.x)[i];
                    float c0 = fminf(fmaxf(x0, -15.f), 15.f);
                    float c1 = fminf(fmaxf(x1, -15.f), 15.f);
                    float e0 = __expf(2.f * c0);
                    float e1 = __expf(2.f * c1);
                    part[mt][i] = __fdividef(e0 - 1.f, e0 + 1.f) * bcol[0]
                                + __fdividef(e1 - 1.f, e1 + 1.f) * bcol[1];
                }
            }
#pragma unroll
            for (int m = 1; m <= 8; m <<= 1)
#pragma unroll
                for (int mt = 0; mt < 2; ++mt)
#pragma unroll
                    for (int i = 0; i < 4; ++i)
                        part[mt][i] += __shfl_xor(part[mt][i], m);
            if (lm == 0) {
#pragma unroll
                for (int mt = 0; mt < 2; ++mt)
#pragma unroll
                    for (int i = 0; i < 4; ++i)
                        Sred[ng * 64 + mg * 32 + mt * 16 + lk * 4 + i] = part[mt][i];
            }
        }
        __syncthreads();                             // B4: Sred ready

        if (t < 64) {
            const int v = v0 + t;
            if (v < VOCAB) Sp[(size_t)esl * VOCAB + v] = Sred[t] + Sred[64 + t];
        }
    }
#undef STAGE
}

// ---------------------------------------------------------------------------
// sum: collapse 5 partial planes into one (coalesced, ~2.4 MB traffic).
// ---------------------------------------------------------------------------
__global__ __launch_bounds__(256) void sum_kernel(
    const float* __restrict__ Sp, float* __restrict__ Ss)
{
    const int v = blockIdx.x * 256 + threadIdx.x;
    if (v < VOCAB)
        Ss[v] = Sp[v] + Sp[VOCAB + v] + Sp[2 * VOCAB + v]
              + Sp[3 * VOCAB + v] + Sp[4 * VOCAB + v];
}

// ---------------------------------------------------------------------------
// attend: per token gather 20 neighbor scores, softmax, weighted emb sum.
// ---------------------------------------------------------------------------
__global__ __launch_bounds__(256) void attend_kernel(
    const int* __restrict__ text, const int* __restrict__ neighbors,
    const float* __restrict__ emb, const float* __restrict__ S,
    float* __restrict__ out)
{
    const int lane = threadIdx.x & 63;
    const int wv   = threadIdx.x >> 6;
    const int tok  = blockIdx.x * 4 + wv;

    const int tid = text[tok];

    int   nbk = 0;
    float sc  = -1e30f;
    if (lane < TOPK) {
        nbk = neighbors[tid * TOPK + lane];
        sc  = S[nbk];
    }

    float mx = sc;
#pragma unroll
    for (int m = 16; m >= 1; m >>= 1)
        mx = fmaxf(mx, __shfl_xor(mx, m));

    float ex = (lane < TOPK) ? expf(sc - mx) : 0.f;
    float sum = ex;
#pragma unroll
    for (int m = 16; m >= 1; m >>= 1)
        sum += __shfl_xor(sum, m);
    float att = ex / sum;

    float acc0 = 0.f, acc1 = 0.f, acc2 = 0.f, acc3 = 0.f, acc4 = 0.f;
    const bool has5 = (lane < EMB - 256);
#pragma unroll 4
    for (int k = 0; k < TOPK; ++k) {
        const float wgt = __shfl(att, k);
        const int   id  = __shfl(nbk, k);
        const float* row = emb + (size_t)id * EMB;
        acc0 = fmaf(wgt, row[lane      ], acc0);
        acc1 = fmaf(wgt, row[lane +  64], acc1);
        acc2 = fmaf(wgt, row[lane + 128], acc2);
        acc3 = fmaf(wgt, row[lane + 192], acc3);
        if (has5) acc4 = fmaf(wgt, row[lane + 256], acc4);
    }

    float* orow = out + (size_t)tok * EMB;
    orow[lane      ] = acc0;
    orow[lane +  64] = acc1;
    orow[lane + 128] = acc2;
    orow[lane + 192] = acc3;
    if (has5) orow[lane + 256] = acc4;
}

extern "C" void kernel_launch(void* const* d_in, const int* in_sizes, int n_in,
                              void* d_out, int out_size, void* d_ws, size_t ws_size,
                              hipStream_t stream) {
    const int*   text      = (const int*)d_in[0];
    const int*   neighbors = (const int*)d_in[1];
    const float* emb       = (const float*)d_in[2];
    const float* A         = (const float*)d_in[3];
    const float* B         = (const float*)d_in[4];
    float*       out       = (float*)d_out;

    char* ws = (char*)d_ws;
    float* Sp = (float*)ws;                 // 5 x 400,000 B partial planes
    float* Ss = (float*)(ws + 2000000);     // 400,000 B summed plane
    short* aT = (short*)(ws + 2400000);     // 204,800 B (16B-aligned)

    prep_kernel<<<320, 256, 0, stream>>>(A, aT);
    score_kernel<<<5 * NVGS, 512, 0, stream>>>(emb, aT, B, Sp);
    sum_kernel<<<(VOCAB + 255) / 256, 256, 0, stream>>>(Sp, Ss);
    attend_kernel<<<NTOK / 4, 256, 0, stream>>>(text, neighbors, emb, Ss, out);
}